// Round 2
// baseline (111.951 us; speedup 1.0000x reference)
//
#include <hip/hip_runtime.h>
#include <hip/hip_bf16.h>

// GlobalPointer logits: x = inputs@W+b -> split q/k per head -> RoPE(q) ->
// logits[b,h,m,n] = <q[b,m,h,:], k[b,n,h,:]> with mask+causal, /8.
// B=8 S=512 DIM=768 H=24 D=64. Output [8][24][512][512] f32.

typedef __bf16 bf16_t;
typedef __attribute__((ext_vector_type(8))) __bf16 bf16x8;
typedef __attribute__((ext_vector_type(4))) float f32x4;

#define NEG_INF 1000000000000.0f

// ws layout (bytes)
#define WS_A   0                  // inputs bf16 [4096][768]   : 6,291,456
#define WS_WT  6291456            // W^T bf16 [3072][768]      : 4,718,592
#define WS_Q   11010048           // Q bf16 [8][24][512][64]   : 12,582,912
#define WS_K   23592960           // K bf16 [8][24][512][64]   : 12,582,912
// total 36,175,872 bytes

__device__ __forceinline__ unsigned short f2bf_bits(float x) {
  union { float f; unsigned u; } v; v.f = x;
  unsigned r = v.u + 0x7FFFu + ((v.u >> 16) & 1u);
  return (unsigned short)(r >> 16);
}

#define GLD16(g, l) __builtin_amdgcn_global_load_lds( \
    (const __attribute__((address_space(1))) void*)(g), \
    (__attribute__((address_space(3))) void*)(l), 16, 0, 0)

// ---------------- fused prep: inputs f32->bf16 + W transpose->bf16 ----------------
// blocks [0,3072): inputs conversion (float4 -> ushort4, 786432 elems)
// blocks [3072,5376): W [768][3072] -> Wt [3072][768] via 32x32 LDS transpose
__global__ void prep_kernel(const float4* __restrict__ in, ushort4* __restrict__ outA,
                            const float* __restrict__ W, unsigned short* __restrict__ Wt) {
  __shared__ float s[32][33];
  if (blockIdx.x < 3072) {
    int i = blockIdx.x * 256 + threadIdx.x;
    float4 v = in[i];
    ushort4 o;
    o.x = f2bf_bits(v.x); o.y = f2bf_bits(v.y);
    o.z = f2bf_bits(v.z); o.w = f2bf_bits(v.w);
    outA[i] = o;
  } else {
    int bid = blockIdx.x - 3072;
    int n0 = (bid % 96) * 32, k0 = (bid / 96) * 32;
    int tx = threadIdx.x & 31, ty = threadIdx.x >> 5; // ty 0..7
#pragma unroll
    for (int r = 0; r < 4; ++r) {
      int k = k0 + ty + r * 8;
      s[ty + r * 8][tx] = W[(size_t)k * 3072 + n0 + tx];
    }
    __syncthreads();
#pragma unroll
    for (int r = 0; r < 4; ++r) {
      int n = ty + r * 8;
      Wt[(size_t)(n0 + n) * 768 + k0 + tx] = f2bf_bits(s[tx][n]);
    }
  }
}

// ---------------- GEMM1: X = A(4096x768) * Wt^T(3072x768), +bias, RoPE(q), split ----------------
// 128x128 tile, 4 waves (2x2 of 64x64), BK=32, mfma 16x16x32 bf16.
// Double-buffered LDS, one barrier per K-step: stage(t+1) || compute(t).
// LDS staged via global_load_lds with pre-swizzled source (slot ^= (row>>1)&3).
__global__ __launch_bounds__(256) void gemm1_kernel(
    const bf16_t* __restrict__ A, const bf16_t* __restrict__ Bt,
    const float* __restrict__ bias,
    unsigned short* __restrict__ Qo, unsigned short* __restrict__ Ko) {
  __shared__ __align__(16) bf16_t As[2 * 128 * 32];
  __shared__ __align__(16) bf16_t Bs[2 * 128 * 32];
  const int tid = threadIdx.x;
  const int lane = tid & 63;
  const int wv = tid >> 6;
  const int wr = (wv >> 1) * 64;
  const int wc = (wv & 1) * 64;

  // bijective XCD swizzle over 768 blocks (768 % 8 == 0): 96 consecutive per XCD
  const int bid = blockIdx.x;
  const int swz = (bid & 7) * 96 + (bid >> 3);
  const int h = swz % 24;              // n-block == head
  const int m0 = (swz / 24) * 128;
  const int n0 = h * 128;

  f32x4 acc[4][4];
#pragma unroll
  for (int i = 0; i < 4; ++i)
#pragma unroll
    for (int j = 0; j < 4; ++j) acc[i][j] = (f32x4){0.f, 0.f, 0.f, 0.f};

  const int srow = lane >> 2;   // row within 16-row chunk
  const int sslot = lane & 3;   // 16B slot within 64B row

  // per-thread staging addresses (row/slot fixed; only k0 and buf vary)
  const int c0 = 2 * wv;        // chunks c0, c0+1
  int rowA0 = 16 * c0 + srow;
  int rowA1 = 16 * (c0 + 1) + srow;
  int fs0 = sslot ^ ((rowA0 >> 1) & 3);
  int fs1 = sslot ^ ((rowA1 >> 1) & 3);
  const bf16_t* gA0 = A + (size_t)(m0 + rowA0) * 768 + fs0 * 8;
  const bf16_t* gA1 = A + (size_t)(m0 + rowA1) * 768 + fs1 * 8;
  const bf16_t* gB0 = Bt + (size_t)(n0 + rowA0) * 768 + fs0 * 8;
  const bf16_t* gB1 = Bt + (size_t)(n0 + rowA1) * 768 + fs1 * 8;

#define STAGE1(buf, k0) do { \
    GLD16(gA0 + (k0), As + (buf) * 4096 + c0 * 512); \
    GLD16(gB0 + (k0), Bs + (buf) * 4096 + c0 * 512); \
    GLD16(gA1 + (k0), As + (buf) * 4096 + (c0 + 1) * 512); \
    GLD16(gB1 + (k0), Bs + (buf) * 4096 + (c0 + 1) * 512); \
  } while (0)

#define COMPUTE1(buf) do { \
    const int kslot = lane >> 4; \
    bf16x8 af[4], bfr[4]; \
    _Pragma("unroll") \
    for (int m16 = 0; m16 < 4; ++m16) { \
      int arow = wr + m16 * 16 + (lane & 15); \
      int sl = kslot ^ ((arow >> 1) & 3); \
      af[m16] = *(const bf16x8*)(As + (buf) * 4096 + arow * 32 + sl * 8); \
    } \
    _Pragma("unroll") \
    for (int n16 = 0; n16 < 4; ++n16) { \
      int brow = wc + n16 * 16 + (lane & 15); \
      int sl = kslot ^ ((brow >> 1) & 3); \
      bfr[n16] = *(const bf16x8*)(Bs + (buf) * 4096 + brow * 32 + sl * 8); \
    } \
    _Pragma("unroll") \
    for (int m16 = 0; m16 < 4; ++m16) \
      _Pragma("unroll") \
      for (int n16 = 0; n16 < 4; ++n16) \
        acc[m16][n16] = __builtin_amdgcn_mfma_f32_16x16x32_bf16( \
            af[m16], bfr[n16], acc[m16][n16], 0, 0, 0); \
  } while (0)

  // 24 K-steps of 32. Prologue stage tile 0; 2-phase pipeline after.
  STAGE1(0, 0);
  __syncthreads();
#pragma unroll 2
  for (int kt = 0; kt < 23; ++kt) {
    const int cur = kt & 1;
    STAGE1(cur ^ 1, (kt + 1) * 32);
    COMPUTE1(cur);
    __syncthreads();   // drains vmcnt for the staged tile; one barrier per K-step
  }
  COMPUTE1(1);

  // epilogue: +bias, RoPE on q half, write bf16 Q / K in [b][h][s][64]
#pragma unroll
  for (int n16 = 0; n16 < 4; ++n16) {
    int c = wc + n16 * 16 + (lane & 15);     // 0..127 within head
    float bv = bias[h * 128 + c];
    bool isq = (c < 64);
    int d = isq ? c : (c - 64);
    float inv = exp2f((float)((c >> 1) & 31) * -0.4152410118609203f); // 10000^(-i/32)
#pragma unroll
    for (int m16 = 0; m16 < 4; ++m16) {
      int rbase = m0 + wr + m16 * 16 + ((lane >> 4) * 4);
#pragma unroll
      for (int r = 0; r < 4; ++r) {
        int mg = rbase + r;
        int s = mg & 511, b = mg >> 9;
        float val = acc[m16][n16][r] + bv;
        float other = __shfl_xor(val, 1, 64);  // partner column c^1 (lane^1)
        float res;
        if (isq) {
          float ang = (float)s * inv;
          float sn, cs;
          sincosf(ang, &sn, &cs);
          res = val * cs + ((c & 1) ? other : -other) * sn;
        } else {
          res = val;
        }
        size_t off = (((size_t)(b * 24 + h) * 512) + s) * 64 + d;
        (isq ? Qo : Ko)[off] = f2bf_bits(res);
      }
    }
  }
#undef STAGE1
#undef COMPUTE1
}

// ---------------- GEMM2: logits[bh] = Q(512x64) * K^T, mask/causal/scale ----------------
// Per block: 128x128 tile of one (b,h). K=64 in one shot (2 mfma k-steps).
__global__ __launch_bounds__(256) void gemm2_kernel(
    const bf16_t* __restrict__ Q, const bf16_t* __restrict__ K,
    const float* __restrict__ mask, float* __restrict__ out) {
  __shared__ __align__(16) bf16_t Qs[128 * 64];
  __shared__ __align__(16) bf16_t Ks[128 * 64];
  const int tid = threadIdx.x;
  const int lane = tid & 63;
  const int wv = tid >> 6;
  const int wr = (wv >> 1) * 64;
  const int wc = (wv & 1) * 64;
  const int bh = blockIdx.z;
  const int b = bh / 24;
  const int m0 = blockIdx.y * 128;
  const int n0 = blockIdx.x * 128;
  const size_t base = (size_t)bh * 512 * 64;

  const int srow = lane >> 3;  // row within 8-row chunk (128B rows)
  const int sslot = lane & 7;
#pragma unroll
  for (int i = 0; i < 4; ++i) {
    int c = 4 * wv + i;                 // chunk 0..15 (8 rows each)
    int row = 8 * c + srow;
    int fslot = sslot ^ (row & 7);      // pre-swizzled source
    const bf16_t* gq = Q + base + (size_t)(m0 + row) * 64 + fslot * 8;
    const bf16_t* gk = K + base + (size_t)(n0 + row) * 64 + fslot * 8;
    GLD16(gq, Qs + c * 512);
    GLD16(gk, Ks + c * 512);
  }
  __syncthreads();

  f32x4 acc[4][4];
#pragma unroll
  for (int i = 0; i < 4; ++i)
#pragma unroll
    for (int j = 0; j < 4; ++j) acc[i][j] = (f32x4){0.f, 0.f, 0.f, 0.f};

#pragma unroll
  for (int kk = 0; kk < 2; ++kk) {
    const int kslot = (lane >> 4) + kk * 4;
    bf16x8 af[4], bfr[4];
#pragma unroll
    for (int m16 = 0; m16 < 4; ++m16) {
      int arow = wr + m16 * 16 + (lane & 15);
      int sl = kslot ^ (arow & 7);
      af[m16] = *(const bf16x8*)(Qs + arow * 64 + sl * 8);
    }
#pragma unroll
    for (int n16 = 0; n16 < 4; ++n16) {
      int brow = wc + n16 * 16 + (lane & 15);
      int sl = kslot ^ (brow & 7);
      bfr[n16] = *(const bf16x8*)(Ks + brow * 64 + sl * 8);
    }
#pragma unroll
    for (int m16 = 0; m16 < 4; ++m16)
#pragma unroll
      for (int n16 = 0; n16 < 4; ++n16)
        acc[m16][n16] = __builtin_amdgcn_mfma_f32_16x16x32_bf16(
            af[m16], bfr[n16], acc[m16][n16], 0, 0, 0);
  }

  const float* mb = mask + (size_t)b * 512;
  float* ob = out + (size_t)bh * 512 * 512;
#pragma unroll
  for (int m16 = 0; m16 < 4; ++m16) {
    int mgb = m0 + wr + m16 * 16 + ((lane >> 4) * 4);
    float mr[4];
#pragma unroll
    for (int r = 0; r < 4; ++r) mr[r] = mb[mgb + r];
#pragma unroll
    for (int n16 = 0; n16 < 4; ++n16) {
      int ng = n0 + wc + n16 * 16 + (lane & 15);
      float mc = mb[ng];
#pragma unroll
      for (int r = 0; r < 4; ++r) {
        int mg = mgb + r;
        float v = acc[m16][n16][r];
        v = v * mr[r] - NEG_INF * (1.0f - mr[r]);
        v = v * mc - NEG_INF * (1.0f - mc);
        if (mg > ng) v -= NEG_INF;   // tril(-1) causal
        v *= 0.125f;                 // / sqrt(64)
        ob[(size_t)mg * 512 + ng] = v;
      }
    }
  }
}

extern "C" void kernel_launch(void* const* d_in, const int* in_sizes, int n_in,
                              void* d_out, int out_size, void* d_ws, size_t ws_size,
                              hipStream_t stream) {
  const float* inputs = (const float*)d_in[0];   // [8][512][768]
  const float* mask = (const float*)d_in[1];     // [8][512]
  const float* W = (const float*)d_in[2];        // [768][3072]
  const float* bias = (const float*)d_in[3];     // [3072]
  float* out = (float*)d_out;                    // [8][24][512][512]
  char* ws = (char*)d_ws;

  bf16_t* Abf = (bf16_t*)(ws + WS_A);
  bf16_t* Wt = (bf16_t*)(ws + WS_WT);
  unsigned short* Qb = (unsigned short*)(ws + WS_Q);
  unsigned short* Kb = (unsigned short*)(ws + WS_K);

  // inputs f32 -> bf16 (3072 blocks) + W -> W^T bf16 (2304 blocks), fused
  prep_kernel<<<5376, 256, 0, stream>>>((const float4*)inputs, (ushort4*)Abf,
                                        W, (unsigned short*)Wt);
  // X = A*W^T + b, RoPE, split -> Q,K bf16 (768 blocks, XCD-swizzled)
  gemm1_kernel<<<768, 256, 0, stream>>>(Abf, Wt, bias, Qb, Kb);
  // logits
  gemm2_kernel<<<dim3(4, 4, 192), 256, 0, stream>>>((const bf16_t*)Qb,
                                                    (const bf16_t*)Kb, mask, out);
}

// Round 3
// 91.578 us; speedup vs baseline: 1.2225x; 1.2225x over previous
//
#include <hip/hip_runtime.h>
#include <hip/hip_bf16.h>

// GlobalPointer logits: x = inputs@W+b -> split q/k per head -> RoPE(q) ->
// logits[b,h,m,n] = <q[b,m,h,:], k[b,n,h,:]> with mask+causal, /8.
// B=8 S=512 DIM=768 H=24 D=64. Output [8][24][512][512] f32.
// GEMM1 in MX-fp8 (e4m3, scale=1.0): 4x less LDS bytes/FLOP + 2x MFMA rate.

typedef __bf16 bf16_t;
typedef __attribute__((ext_vector_type(8))) __bf16 bf16x8;
typedef __attribute__((ext_vector_type(4))) float f32x4;
typedef __attribute__((ext_vector_type(8))) int i32x8;

#define NEG_INF 1000000000000.0f

// ws layout (bytes)
#define WS_A8   0                  // inputs fp8 [4096][768]    : 3,145,728
#define WS_WT8  3145728            // W^T fp8 [3072][768]       : 2,359,296
#define WS_Q    5505024            // Q bf16 [8][24][512][64]   : 12,582,912
#define WS_K    18087936           // K bf16 [8][24][512][64]   : 12,582,912
// total 30,670,848 bytes

__device__ __forceinline__ unsigned short f2bf_bits(float x) {
  union { float f; unsigned u; } v; v.f = x;
  unsigned r = v.u + 0x7FFFu + ((v.u >> 16) & 1u);
  return (unsigned short)(r >> 16);
}

__device__ __forceinline__ int pack4_fp8(float a, float b, float c, float d) {
  int w = __builtin_amdgcn_cvt_pk_fp8_f32(a, b, 0, false);   // bytes 0,1
  w = __builtin_amdgcn_cvt_pk_fp8_f32(c, d, w, true);        // bytes 2,3
  return w;
}

#define GLD16(g, l) __builtin_amdgcn_global_load_lds( \
    (const __attribute__((address_space(1))) void*)(g), \
    (__attribute__((address_space(3))) void*)(l), 16, 0, 0)

// ---------------- fused prep: inputs f32->fp8 + W transpose->fp8 ----------------
// blocks [0,768): inputs conversion (16 floats/thread -> int4 of 16 fp8)
// blocks [768,3072): W [768][3072] -> Wt [3072][768] fp8 via 32x32 LDS transpose
__global__ void prep_kernel(const float4* __restrict__ in, int4* __restrict__ outA,
                            const float* __restrict__ W, char* __restrict__ Wt8) {
  __shared__ float s[32][33];
  if (blockIdx.x < 768) {
    int g = blockIdx.x * 256 + threadIdx.x;   // thread handles 16 floats
    float4 v0 = in[g * 4 + 0];
    float4 v1 = in[g * 4 + 1];
    float4 v2 = in[g * 4 + 2];
    float4 v3 = in[g * 4 + 3];
    int4 o;
    o.x = pack4_fp8(v0.x, v0.y, v0.z, v0.w);
    o.y = pack4_fp8(v1.x, v1.y, v1.z, v1.w);
    o.z = pack4_fp8(v2.x, v2.y, v2.z, v2.w);
    o.w = pack4_fp8(v3.x, v3.y, v3.z, v3.w);
    outA[g] = o;
  } else {
    int bid = blockIdx.x - 768;
    int n0 = (bid % 96) * 32, k0 = (bid / 96) * 32;
    int tx = threadIdx.x & 31, ty = threadIdx.x >> 5; // ty 0..7
#pragma unroll
    for (int r = 0; r < 4; ++r) {
      int k = k0 + ty + r * 8;
      s[ty + r * 8][tx] = W[(size_t)k * 3072 + n0 + tx];
    }
    __syncthreads();
    // write: thread (kx 0..7, tn 0..31) -> 4 consecutive k-bytes of row n0+tn
    int kx = threadIdx.x & 7, tn = threadIdx.x >> 3;
    int w = pack4_fp8(s[4 * kx + 0][tn], s[4 * kx + 1][tn],
                      s[4 * kx + 2][tn], s[4 * kx + 3][tn]);
    *(int*)(Wt8 + (size_t)(n0 + tn) * 768 + k0 + 4 * kx) = w;
  }
}

// ---------------- GEMM1 (MX-fp8): X = A(4096x768) * Wt^T(3072x768), +bias, RoPE(q), split ----
// 128x128 tile, 4 waves (2x2 of 64x64), BK=128, mfma_scale 16x16x128 f8f6f4 (fp8/fp8).
// LDS rows are 128B (8 x 16B slots); XOR swizzle slot ^= (row&7), both-sides
// (pre-swizzled global source for global_load_lds + swizzled ds_read). 2-phase dbuf.
__global__ __launch_bounds__(256) void gemm1_kernel(
    const char* __restrict__ A8, const char* __restrict__ Bt8,
    const float* __restrict__ bias,
    unsigned short* __restrict__ Qo, unsigned short* __restrict__ Ko) {
  __shared__ __align__(16) char As[2][128 * 128];
  __shared__ __align__(16) char Bs[2][128 * 128];
  const int tid = threadIdx.x;
  const int lane = tid & 63;
  const int wv = tid >> 6;
  const int wr = (wv >> 1) * 64;
  const int wc = (wv & 1) * 64;

  // bijective XCD swizzle over 768 blocks (768 % 8 == 0): 96 consecutive per XCD
  const int bid = blockIdx.x;
  const int swz = (bid & 7) * 96 + (bid >> 3);
  const int h = swz % 24;              // n-block == head
  const int m0 = (swz / 24) * 128;
  const int n0 = h * 128;

  f32x4 acc[4][4];
#pragma unroll
  for (int i = 0; i < 4; ++i)
#pragma unroll
    for (int j = 0; j < 4; ++j) acc[i][j] = (f32x4){0.f, 0.f, 0.f, 0.f};

  // staging: 32 chunks of 1KB (8 rows x 128B each); wave w stages A chunks
  // 4w..4w+3 and B chunks 4w..4w+3. lane -> row = c*8 + lane>>3, slot = lane&7.
  // source k-byte pre-swizzled: (slot ^ (row&7))*16.
  const char* pA[4];
  const char* pB[4];
#pragma unroll
  for (int i = 0; i < 4; ++i) {
    int c = 4 * wv + i;
    int row = c * 8 + (lane >> 3);
    int srcslot = (lane & 7) ^ (row & 7);
    pA[i] = A8 + (size_t)(m0 + row) * 768 + srcslot * 16;
    pB[i] = Bt8 + (size_t)(n0 + row) * 768 + srcslot * 16;
  }

#define STAGE1(buf, k0) do { \
    _Pragma("unroll") \
    for (int i = 0; i < 4; ++i) { \
      GLD16(pA[i] + (k0), As[buf] + (4 * wv + i) * 1024); \
      GLD16(pB[i] + (k0), Bs[buf] + (4 * wv + i) * 1024); \
    } \
  } while (0)

#define COMPUTE1(buf) do { \
    const int t = lane >> 4; \
    i32x8 af[4], bfr[4]; \
    _Pragma("unroll") \
    for (int m16 = 0; m16 < 4; ++m16) { \
      int row = wr + m16 * 16 + (lane & 15); \
      int x = row & 7; \
      const char* rb = As[buf] + row * 128; \
      int4 lo = *(const int4*)(rb + ((2 * t) ^ x) * 16); \
      int4 hi = *(const int4*)(rb + ((2 * t + 1) ^ x) * 16); \
      af[m16] = (i32x8){lo.x, lo.y, lo.z, lo.w, hi.x, hi.y, hi.z, hi.w}; \
    } \
    _Pragma("unroll") \
    for (int n16 = 0; n16 < 4; ++n16) { \
      int row = wc + n16 * 16 + (lane & 15); \
      int x = row & 7; \
      const char* rb = Bs[buf] + row * 128; \
      int4 lo = *(const int4*)(rb + ((2 * t) ^ x) * 16); \
      int4 hi = *(const int4*)(rb + ((2 * t + 1) ^ x) * 16); \
      bfr[n16] = (i32x8){lo.x, lo.y, lo.z, lo.w, hi.x, hi.y, hi.z, hi.w}; \
    } \
    _Pragma("unroll") \
    for (int m16 = 0; m16 < 4; ++m16) \
      _Pragma("unroll") \
      for (int n16 = 0; n16 < 4; ++n16) \
        acc[m16][n16] = __builtin_amdgcn_mfma_scale_f32_16x16x128_f8f6f4( \
            af[m16], bfr[n16], acc[m16][n16], 0, 0, \
            0, 0x7F7F7F7F, 0, 0x7F7F7F7F); \
  } while (0)

  // 6 K-steps of 128. Prologue stage tile 0; 2-phase pipeline after.
  STAGE1(0, 0);
  __syncthreads();
#pragma unroll
  for (int kt = 0; kt < 5; ++kt) {
    const int cur = kt & 1;
    STAGE1(cur ^ 1, (kt + 1) * 128);
    COMPUTE1(cur);
    __syncthreads();   // drains vmcnt for the staged tile; one barrier per K-step
  }
  COMPUTE1(1);

  // epilogue: +bias, RoPE on q half, write bf16 Q / K in [b][h][s][64]
#pragma unroll
  for (int n16 = 0; n16 < 4; ++n16) {
    int c = wc + n16 * 16 + (lane & 15);     // 0..127 within head
    float bv = bias[h * 128 + c];
    bool isq = (c < 64);
    int d = isq ? c : (c - 64);
    float inv = exp2f((float)((c >> 1) & 31) * -0.4152410118609203f); // 10000^(-i/32)
#pragma unroll
    for (int m16 = 0; m16 < 4; ++m16) {
      int rbase = m0 + wr + m16 * 16 + ((lane >> 4) * 4);
#pragma unroll
      for (int r = 0; r < 4; ++r) {
        int mg = rbase + r;
        int s = mg & 511, b = mg >> 9;
        float val = acc[m16][n16][r] + bv;
        float other = __shfl_xor(val, 1, 64);  // partner column c^1 (lane^1)
        float res;
        if (isq) {
          float ang = (float)s * inv;
          float sn, cs;
          sincosf(ang, &sn, &cs);
          res = val * cs + ((c & 1) ? other : -other) * sn;
        } else {
          res = val;
        }
        size_t off = (((size_t)(b * 24 + h) * 512) + s) * 64 + d;
        (isq ? Qo : Ko)[off] = f2bf_bits(res);
      }
    }
  }
#undef STAGE1
#undef COMPUTE1
}

// ---------------- GEMM2: logits[bh] = Q(512x64) * K^T, mask/causal/scale ----------------
// Per block: 128x128 tile of one (b,h). K=64 in one shot (2 mfma k-steps).
__global__ __launch_bounds__(256) void gemm2_kernel(
    const bf16_t* __restrict__ Q, const bf16_t* __restrict__ K,
    const float* __restrict__ mask, float* __restrict__ out) {
  __shared__ __align__(16) bf16_t Qs[128 * 64];
  __shared__ __align__(16) bf16_t Ks[128 * 64];
  const int tid = threadIdx.x;
  const int lane = tid & 63;
  const int wv = tid >> 6;
  const int wr = (wv >> 1) * 64;
  const int wc = (wv & 1) * 64;
  const int bh = blockIdx.z;
  const int b = bh / 24;
  const int m0 = blockIdx.y * 128;
  const int n0 = blockIdx.x * 128;
  const size_t base = (size_t)bh * 512 * 64;

  const int srow = lane >> 3;  // row within 8-row chunk (128B rows)
  const int sslot = lane & 7;
#pragma unroll
  for (int i = 0; i < 4; ++i) {
    int c = 4 * wv + i;                 // chunk 0..15 (8 rows each)
    int row = 8 * c + srow;
    int fslot = sslot ^ (row & 7);      // pre-swizzled source
    const bf16_t* gq = Q + base + (size_t)(m0 + row) * 64 + fslot * 8;
    const bf16_t* gk = K + base + (size_t)(n0 + row) * 64 + fslot * 8;
    GLD16(gq, Qs + c * 512);
    GLD16(gk, Ks + c * 512);
  }
  __syncthreads();

  f32x4 acc[4][4];
#pragma unroll
  for (int i = 0; i < 4; ++i)
#pragma unroll
    for (int j = 0; j < 4; ++j) acc[i][j] = (f32x4){0.f, 0.f, 0.f, 0.f};

#pragma unroll
  for (int kk = 0; kk < 2; ++kk) {
    const int kslot = (lane >> 4) + kk * 4;
    bf16x8 af[4], bfr[4];
#pragma unroll
    for (int m16 = 0; m16 < 4; ++m16) {
      int arow = wr + m16 * 16 + (lane & 15);
      int sl = kslot ^ (arow & 7);
      af[m16] = *(const bf16x8*)(Qs + arow * 64 + sl * 8);
    }
#pragma unroll
    for (int n16 = 0; n16 < 4; ++n16) {
      int brow = wc + n16 * 16 + (lane & 15);
      int sl = kslot ^ (brow & 7);
      bfr[n16] = *(const bf16x8*)(Ks + brow * 64 + sl * 8);
    }
#pragma unroll
    for (int m16 = 0; m16 < 4; ++m16)
#pragma unroll
      for (int n16 = 0; n16 < 4; ++n16)
        acc[m16][n16] = __builtin_amdgcn_mfma_f32_16x16x32_bf16(
            af[m16], bfr[n16], acc[m16][n16], 0, 0, 0);
  }

  const float* mb = mask + (size_t)b * 512;
  float* ob = out + (size_t)bh * 512 * 512;
#pragma unroll
  for (int m16 = 0; m16 < 4; ++m16) {
    int mgb = m0 + wr + m16 * 16 + ((lane >> 4) * 4);
    float mr[4];
#pragma unroll
    for (int r = 0; r < 4; ++r) mr[r] = mb[mgb + r];
#pragma unroll
    for (int n16 = 0; n16 < 4; ++n16) {
      int ng = n0 + wc + n16 * 16 + (lane & 15);
      float mc = mb[ng];
#pragma unroll
      for (int r = 0; r < 4; ++r) {
        int mg = mgb + r;
        float v = acc[m16][n16][r];
        v = v * mr[r] - NEG_INF * (1.0f - mr[r]);
        v = v * mc - NEG_INF * (1.0f - mc);
        if (mg > ng) v -= NEG_INF;   // tril(-1) causal
        v *= 0.125f;                 // / sqrt(64)
        ob[(size_t)mg * 512 + ng] = v;
      }
    }
  }
}

extern "C" void kernel_launch(void* const* d_in, const int* in_sizes, int n_in,
                              void* d_out, int out_size, void* d_ws, size_t ws_size,
                              hipStream_t stream) {
  const float* inputs = (const float*)d_in[0];   // [8][512][768]
  const float* mask = (const float*)d_in[1];     // [8][512]
  const float* W = (const float*)d_in[2];        // [768][3072]
  const float* bias = (const float*)d_in[3];     // [3072]
  float* out = (float*)d_out;                    // [8][24][512][512]
  char* ws = (char*)d_ws;

  char* A8 = ws + WS_A8;
  char* Wt8 = ws + WS_WT8;
  unsigned short* Qb = (unsigned short*)(ws + WS_Q);
  unsigned short* Kb = (unsigned short*)(ws + WS_K);

  // inputs f32 -> fp8 (768 blocks) + W -> W^T fp8 (2304 blocks), fused
  prep_kernel<<<3072, 256, 0, stream>>>((const float4*)inputs, (int4*)A8, W, Wt8);
  // X = A*W^T + b (MX-fp8), RoPE, split -> Q,K bf16 (768 blocks, XCD-swizzled)
  gemm1_kernel<<<768, 256, 0, stream>>>(A8, Wt8, bias, Qb, Kb);
  // logits
  gemm2_kernel<<<dim3(4, 4, 192), 256, 0, stream>>>((const bf16_t*)Qb,
                                                    (const bf16_t*)Kb, mask, out);
}